// Round 7
// baseline (210.434 us; speedup 1.0000x reference)
//
#include <hip/hip_runtime.h>
#include <hip/hip_bf16.h>

#define NB 16
#define NS 2048
#define ND 768
#define NG 1024
#define ROWS (NB * NG)            // 16384 output rows (b*G + g)

#define BM 128
#define BN 128
#define BK 32
#define NT (ND / BK)              // 24 K-tiles
#define NCB (ND / BN)             // 6 col-strips
#define NRB (ROWS / BM)           // 128 row-bands
#define ROWSTRIDE ((long)64 * ND * 2)   // 64 rows of bf16 [*,768]

typedef __attribute__((ext_vector_type(8))) __bf16 bf16x8;
typedef __attribute__((ext_vector_type(8))) unsigned short ushort8_t;
typedef __attribute__((ext_vector_type(4))) float f32x4;

__device__ __forceinline__ unsigned short f2bf(float f) {
    unsigned int u = __builtin_bit_cast(unsigned int, f);
    return (unsigned short)((u + 0x7FFFu + ((u >> 16) & 1u)) >> 16);   // RNE
}

__device__ __forceinline__ void gload_lds16(const void* g, void* l) {
    __builtin_amdgcn_global_load_lds((const __attribute__((address_space(1))) unsigned int*)g,
                                     (__attribute__((address_space(3))) unsigned int*)l, 16, 0, 0);
}

__device__ __forceinline__ float fast_tanh(float v) {
    float x = fminf(fmaxf(v, -15.f), 15.f);
    float e = __expf(2.f * x);
    return (e - 1.f) / (e + 1.f);
}

#define VMCNT4   asm volatile("s_waitcnt vmcnt(4)" ::: "memory")
#define VMCNT0   asm volatile("s_waitcnt vmcnt(0)" ::: "memory")
#define LGKMCNT0 asm volatile("s_waitcnt lgkmcnt(0)" ::: "memory")

// ---- pair-mean + bf16 cast: mean[b*G+g][d] = 0.5*(x[b][2g][d]+x[b][2g+1][d]); 8 outs/thread
__global__ __launch_bounds__(256) void mean_cast_kernel(const float* __restrict__ x,
                                                        unsigned short* __restrict__ mbf) {
    long e = ((long)blockIdx.x * 256 + threadIdx.x) * 8;   // over ROWS*ND
    int gg = (int)(e / ND);
    int d  = (int)(e - (long)gg * ND);
    int b = gg >> 10, g = gg & (NG - 1);
    const float* p0 = x + ((long)(b * NS + 2 * g)) * ND + d;
    float4 u0 = *(const float4*)p0;
    float4 u1 = *(const float4*)(p0 + 4);
    float4 v0 = *(const float4*)(p0 + ND);
    float4 v1 = *(const float4*)(p0 + ND + 4);
    ushort8_t o;
    #pragma unroll
    for (int j = 0; j < 4; ++j) {
        o[j]     = f2bf(0.5f * (u0[j] + v0[j]));
        o[4 + j] = f2bf(0.5f * (u1[j] + v1[j]));
    }
    *(ushort8_t*)(mbf + e) = o;
}

// ---- transpose-cast W (768x768 f32 [k][n]) to bf16 [n][k]
__global__ __launch_bounds__(256) void wtrans_kernel(const float* __restrict__ W,
                                                     unsigned short* __restrict__ Bt) {
    __shared__ float tile[64][65];
    int n0 = blockIdx.x * 64;
    int k0 = blockIdx.y * 64;
    int tx = threadIdx.x & 63;
    int ty = threadIdx.x >> 6;    // 0..3
    #pragma unroll
    for (int i = 0; i < 64; i += 4)
        tile[ty + i][tx] = W[(long)(k0 + ty + i) * ND + n0 + tx];
    __syncthreads();
    #pragma unroll
    for (int i = 0; i < 64; i += 4)
        Bt[(long)(n0 + ty + i) * ND + k0 + tx] = f2bf(tile[tx][ty + i]);
}

// ---- GEMM: out[r][c] = tanh( sum_k A[r][k]*Bt[c][k] + b[c] )
// 128x128, BK=32, 4 waves 2x2 (wave tile 64x64, 4x4 frags of 16x16x32).
// Both operands via global_load_lds, double-buffered, counted vmcnt(4): tile t+1's
// loads are in flight across the whole compute of tile t (no reg round-trips).
// XOR chunk swizzle on the GLOBAL source (within-64B row -> coalescing kept),
// LDS dest strictly tid*16 linear (m104); frag reads use the inverse swizzle.
__global__ __launch_bounds__(256, 3) void gemm_kernel(const unsigned short* __restrict__ A,
                                                      const unsigned short* __restrict__ Bt,
                                                      const float* __restrict__ bias,
                                                      float* __restrict__ out) {
    __shared__ unsigned short Al[2][BM * BK];   // 2 x 8 KB
    __shared__ unsigned short Bl[2][BN * BK];   // 2 x 8 KB
    int tid = threadIdx.x;
    int lane = tid & 63;
    int w = tid >> 6;
    int wr = w >> 1, wc = w & 1;
    int r = lane & 15, h = lane >> 4;

    // bijective XCD swizzle: 768 = 8 xcds * 96; band = (s/6)*8 + xcd, c = s%6
    int bid = blockIdx.x;
    int xcd = bid & 7;
    int s = bid >> 3;                        // 0..95
    int c = s % NCB;
    int band = (s / NCB) * 8 + xcd;          // 0..127
    int row0 = band * BM;
    int col0 = c * BN;

    // staging: chunk i in {0,1}: src row = base + i*64 + (tid>>2), 16B slot = swz
    int swz = (tid & 3) ^ ((tid >> 3) & 3);
    const char* gA = (const char*)A  + ((long)(row0 + (tid >> 2))) * (ND * 2) + swz * 16;
    const char* gB = (const char*)Bt + ((long)(col0 + (tid >> 2))) * (ND * 2) + swz * 16;

    // fragment read offsets (swizzled): LDS[row][slot] = global[row][slot ^ ((row>>1)&3)]
    int aoff[4], boff[4];
    #pragma unroll
    for (int m = 0; m < 4; ++m) {
        int row = wr * 64 + m * 16 + r;
        aoff[m] = row * 64 + ((h ^ ((row >> 1) & 3)) * 16);
    }
    #pragma unroll
    for (int n = 0; n < 4; ++n) {
        int row = wc * 64 + n * 16 + r;
        boff[n] = row * 64 + ((h ^ ((row >> 1) & 3)) * 16);
    }

#define STAGE(KT, CUR) do { \
        long kb = (long)(KT) * (BK * 2); \
        gload_lds16(gA + kb,             (char*)&Al[CUR][0] + tid * 16); \
        gload_lds16(gA + kb + ROWSTRIDE, (char*)&Al[CUR][0] + 4096 + tid * 16); \
        gload_lds16(gB + kb,             (char*)&Bl[CUR][0] + tid * 16); \
        gload_lds16(gB + kb + ROWSTRIDE, (char*)&Bl[CUR][0] + 4096 + tid * 16); \
    } while (0)

    f32x4 acc[4][4] = {};

    STAGE(0, 0);                              // prologue: tile 0 in flight
    for (int t = 0; t < NT; ++t) {
        int cur = t & 1;
        LGKMCNT0;                             // my ds_reads of buf cur^1 retired
        __builtin_amdgcn_s_barrier();         // B1: all waves done with buf cur^1
        if (t + 1 < NT) {
            STAGE(t + 1, cur ^ 1);            // overwrite now-free buffer
            VMCNT4;                           // tile t landed; t+1 stays in flight
        } else {
            VMCNT0;                           // last tile
        }
        __builtin_amdgcn_s_barrier();         // B2: tile t visible to all waves
        const char* ab = (const char*)&Al[cur][0];
        const char* bb = (const char*)&Bl[cur][0];
        bf16x8 af[4];
        #pragma unroll
        for (int m = 0; m < 4; ++m)
            af[m] = __builtin_bit_cast(bf16x8, *(const ushort8_t*)(ab + aoff[m]));
        #pragma unroll
        for (int n = 0; n < 4; ++n) {
            bf16x8 bv = __builtin_bit_cast(bf16x8, *(const ushort8_t*)(bb + boff[n]));
            #pragma unroll
            for (int m = 0; m < 4; ++m)
                acc[m][n] = __builtin_amdgcn_mfma_f32_16x16x32_bf16(af[m], bv, acc[m][n], 0, 0, 0);
        }
    }
#undef STAGE

    float bv[4];
    #pragma unroll
    for (int n = 0; n < 4; ++n) bv[n] = bias[col0 + wc * 64 + n * 16 + r];

    #pragma unroll
    for (int m = 0; m < 4; ++m) {
        #pragma unroll
        for (int q = 0; q < 4; ++q) {
            int orow = row0 + wr * 64 + m * 16 + h * 4 + q;
            float* op = out + (long)orow * ND + col0 + wc * 64 + r;
            #pragma unroll
            for (int n = 0; n < 4; ++n)
                __builtin_nontemporal_store(fast_tanh(acc[m][n][q] + bv[n]), op + n * 16);
        }
    }
}

// ---- per-group masks + per-block partial sums
__global__ __launch_bounds__(256) void masks_kernel(const int* __restrict__ padding,
                                                    const int* __restrict__ regular,
                                                    const int* __restrict__ seqpair,
                                                    float* __restrict__ out_mp,
                                                    float* __restrict__ out_mr,
                                                    float* __restrict__ out_ms,
                                                    int2* __restrict__ partials) {
    int i = blockIdx.x * 256 + threadIdx.x;      // over ROWS
    int b = i >> 10, g = i & (NG - 1);
    int t = b * NS + 2 * g;
    int r0 = regular[t], r1 = regular[t + 1];
    int p  = ((padding[t] | padding[t + 1]) != 0) ? 1 : 0;
    int mr = ((r0 | r1) != 0) ? 1 : 0;
    int ms = ((seqpair[t] > 0) && (seqpair[t + 1] > 0)) ? 1 : 0;
    if (p == 0) ms = -1;
    out_mp[i] = (float)p;
    out_mr[i] = (float)mr;
    out_ms[i] = (float)ms;

    int mrs = mr, tok = r0 + r1;
    #pragma unroll
    for (int off = 32; off > 0; off >>= 1) {
        mrs += __shfl_down(mrs, off);
        tok += __shfl_down(tok, off);
    }
    __shared__ int sm[4], st[4];
    int wv = threadIdx.x >> 6, lane = threadIdx.x & 63;
    if (lane == 0) { sm[wv] = mrs; st[wv] = tok; }
    __syncthreads();
    if (threadIdx.x == 0)
        partials[blockIdx.x] = make_int2(sm[0] + sm[1] + sm[2] + sm[3],
                                         st[0] + st[1] + st[2] + st[3]);
}

// ---- compression_rate from 64 per-block partials (single wave)
__global__ void cr_kernel(const int2* __restrict__ partials, float* __restrict__ cr) {
    int2 p = partials[threadIdx.x];
    int a = p.x, t = p.y;
    #pragma unroll
    for (int off = 32; off > 0; off >>= 1) {
        a += __shfl_down(a, off);
        t += __shfl_down(t, off);
    }
    if (threadIdx.x == 0) cr[0] = (float)a / (float)t;
}

extern "C" void kernel_launch(void* const* d_in, const int* in_sizes, int n_in,
                              void* d_out, int out_size, void* d_ws, size_t ws_size,
                              hipStream_t stream) {
    const float* x        = (const float*)d_in[0];
    const int*   padding  = (const int*)d_in[2];
    const int*   regular  = (const int*)d_in[3];
    const int*   seqpair  = (const int*)d_in[4];
    const float* W        = (const float*)d_in[6];
    const float* bias     = (const float*)d_in[7];

    float* outc   = (float*)d_out;                       // compact (B,G,D)
    float* out_mp = outc + (long)ROWS * ND;              // mask_padding (B,G)
    float* out_mr = out_mp + ROWS;                       // mask_regular (B,G)
    float* out_ms = out_mr + ROWS;                       // mask_seq_pair (B,G)
    float* out_cr = out_ms + ROWS;                       // compression_rate (1)

    unsigned short* mbf = (unsigned short*)d_ws;                          // 25165824 B
    unsigned short* wbt = (unsigned short*)((char*)d_ws + 25165824);      // 1179648 B
    int2* partials = (int2*)((char*)d_ws + 25165824 + 1179648);           // 64 * 8 B

    wtrans_kernel<<<dim3(ND / 64, ND / 64), 256, 0, stream>>>(W, wbt);
    mean_cast_kernel<<<(int)(((long)ROWS * ND / 8) / 256), 256, 0, stream>>>(x, mbf);
    masks_kernel<<<ROWS / 256, 256, 0, stream>>>(padding, regular, seqpair, out_mp, out_mr, out_ms, partials);
    gemm_kernel<<<NCB * NRB, 256, 0, stream>>>(mbf, wbt, bias, outc);
    cr_kernel<<<1, 64, 0, stream>>>(partials, out_cr);
}